// Round 12
// baseline (120.349 us; speedup 1.0000x reference)
//
#include <hip/hip_runtime.h>

// adder2d: out[b,f,l] = -sum_k |W[f,k] - P[b,k,l]|, P = 3x3/s1/p1 im2col of x.
// Round-12: r11 numerics/staging/barrier kept; wave decomposition changed to
// 2-wave (128-thr) blocks, per-thread tile 8m x 8f (64 acc): 4 ds_read_b128
// per 64 v_sad_u16 (halves the LDS-read stream vs r11's 3 per 32) and 2x the
// independent sads per read. Grid (196,1,8) = 1568 2-wave blocks (same 12.25
// waves/CU, 87.5% balance). P: 18 gathers/thread, prefetched; W: 9 float4
// row-loads/thread direct from L2 (no reg prefetch -> no spill), each thread
// packs its own 18 (c,c+2) pair-words. u16 quant scale 4096 bias 32768.

#define B_    16
#define C_    128
#define HH    28
#define WW    28
#define F_    128
#define L_    (HH * WW)          // 784
#define K_    (C_ * 9)           // 1152
#define M_    (B_ * L_)          // 12544 = 196 * 64 exactly
#define TM    64
#define BC    4                  // channels per chunk
#define KC    (BC * 9)           // 36 k per chunk
#define KP    (KC / 2)           // 18 packed pairs per chunk
#define SLAB  (B_ * F_ * L_)     // 1,605,632 floats per partial slab
#define NMT   (M_ / TM)          // 196 m-tiles
#define QS    4096.0f            // u16 quantization scale (range +-8)
#define QB    32768.5f           // bias + 0.5 (round-half-up via cvt floor)

__device__ __forceinline__ unsigned sad16(unsigned a, unsigned b, unsigned c) {
    // D = |a.lo16 - b.lo16| + |a.hi16 - b.hi16| + c   (2 elems / inst)
    asm("v_sad_u16 %0, %1, %2, %0" : "+v"(c) : "v"(a), "v"(b));
    return c;
}

__global__ __launch_bounds__(128, 2)
void adder2d_main(const float* __restrict__ x, const float* __restrict__ Wg,
                  float* __restrict__ dst, int nch, int direct) {
    __shared__ __align__(16) unsigned Plq[2][KP][TM];   //  9,216 B
    __shared__ __align__(16) unsigned Wlq[2][KP][F_];   // 18,432 B

    const int t    = threadIdx.x;       // 0..127
    const int lane = t & 63;
    const int w    = t >> 6;            // wave 0/1
    const int tx   = lane & 7;          // m-group: 8 m each
    const int ty   = lane >> 3;         // f-group: 8 f each
    const int fw   = 64 * w;            // wave's f half
    const int mt   = blockIdx.x, sp = blockIdx.z;
    const int c0   = sp * nch * BC;

    // ---- P identity: lane owns m = mt*64 + lane (same set in both waves) ----
    const int m  = mt * TM + lane;
    const int b  = m / L_;
    const int l  = m - b * L_;
    const int ho = l / WW, wo = l - ho * WW;
    int   toff[9];
    float sc[9];
    #pragma unroll
    for (int r = 0; r < 9; ++r) {
        const int dy = r / 3 - 1;
        const int dx = r - (r / 3) * 3 - 1;
        const bool ok = ((unsigned)(ho + dy) < (unsigned)HH) &&
                        ((unsigned)(wo + dx) < (unsigned)WW);
        toff[r] = ok ? (dy * WW + dx) : 0;   // safe addr; zeroed by sc
        sc[r]   = ok ? QS : 0.0f;            // masked -> quantize(0) = bias
    }
    const float* xb = x + (size_t)b * (C_ * L_) + l;

    // ---- staging roles ----
    // P: wave w stages pair cp = w: channels (c8+w, c8+w+2), taps 0..8.
    // W: thread t stages row f = t: 9 float4 loads -> 18 pair-words.
    const float* wrow = Wg + (size_t)t * K_;

    unsigned acc[8][8];
    #pragma unroll
    for (int i = 0; i < 8; ++i)
        #pragma unroll
        for (int j = 0; j < 8; ++j) acc[i][j] = 0u;

    float ppre[18];
    auto loadP = [&](int c8) {
        const float* x1 = xb + (size_t)(c8 + w) * L_;
        const float* x2 = x1 + 2 * L_;
        #pragma unroll
        for (int r = 0; r < 9; ++r) {
            ppre[r]     = x1[toff[r]];
            ppre[9 + r] = x2[toff[r]];
        }
    };

    loadP(c0);

    #pragma unroll 1
    for (int ch = 0; ch < nch; ++ch) {
        const int bufi = ch & 1;
        const int c8 = c0 + ch * BC;
        // ---- stage P from prefetch regs (quantize + pack inline) ----
        #pragma unroll
        for (int r = 0; r < 9; ++r) {
            const unsigned qlo = (unsigned)__builtin_fmaf(ppre[r],     sc[r], QB);
            const unsigned qhi = (unsigned)__builtin_fmaf(ppre[9 + r], sc[r], QB);
            Plq[bufi][w * 9 + r][lane] = (qlo & 0xffffu) | (qhi << 16);
        }
        // ---- stage W direct from L2: 9 float4 loads, pack 18 words ----
        {
            const float4* wc = (const float4*)(wrow + (size_t)c8 * 9);
            float wf[36];                          // constant-indexed -> regs
            #pragma unroll
            for (int i = 0; i < 9; ++i) {
                const float4 v = wc[i];
                wf[4 * i + 0] = v.x; wf[4 * i + 1] = v.y;
                wf[4 * i + 2] = v.z; wf[4 * i + 3] = v.w;
            }
            #pragma unroll
            for (int cp = 0; cp < 2; ++cp)
                #pragma unroll
                for (int r = 0; r < 9; ++r) {
                    const unsigned qlo =
                        (unsigned)__builtin_fmaf(wf[cp * 9 + r],      QS, QB);
                    const unsigned qhi =
                        (unsigned)__builtin_fmaf(wf[cp * 9 + r + 18], QS, QB);
                    Wlq[bufi][cp * 9 + r][t] = (qlo & 0xffffu) | (qhi << 16);
                }
        }
        // ---- prefetch next chunk P (stays in flight across the barrier) ----
        if (ch + 1 < nch) loadP(c8 + BC);
        // ---- barrier: LDS writes drained, vmcnt NOT drained ----
        asm volatile("s_waitcnt lgkmcnt(0)" ::: "memory");
        __builtin_amdgcn_s_barrier();
        asm volatile("" ::: "memory");
        __builtin_amdgcn_sched_barrier(0);
        // ---- compute: 18 kp x (4 ds_read_b128 + 64 v_sad_u16) ----
        #pragma unroll 3
        for (int kp = 0; kp < KP; ++kp) {
            const uint4 pA = *(const uint4*)&Plq[bufi][kp][tx * 8];
            const uint4 pB = *(const uint4*)&Plq[bufi][kp][tx * 8 + 4];
            const uint4 wA = *(const uint4*)&Wlq[bufi][kp][fw + ty * 8];
            const uint4 wB = *(const uint4*)&Wlq[bufi][kp][fw + ty * 8 + 4];
            const unsigned pm[8] = {pA.x, pA.y, pA.z, pA.w,
                                    pB.x, pB.y, pB.z, pB.w};
            const unsigned wn[8] = {wA.x, wA.y, wA.z, wA.w,
                                    wB.x, wB.y, wB.z, wB.w};
            #pragma unroll
            for (int i = 0; i < 8; ++i)
                #pragma unroll
                for (int j = 0; j < 8; ++j)
                    acc[i][j] = sad16(pm[i], wn[j], acc[i][j]);
        }
        // no trailing barrier: next iter writes the OTHER buffer; a wave can
        // only re-write THIS buffer after the next barrier, whose lgkmcnt(0)
        // has drained every wave's reads of it (r11-proven).
    }

    // ---- store: thread covers m = mt*64 + tx*8 .. +8 (8 | 784: no straddle)
    const int mb = mt * TM + tx * 8;
    const int bI = mb / L_;
    const int lb = mb - bI * L_;
    float* slab = direct ? dst : dst + (size_t)sp * SLAB;
    const float qs = (direct ? -1.0f : 1.0f) / QS;   // dequant + sign fold
    #pragma unroll
    for (int j = 0; j < 8; ++j) {
        const int f = fw + ty * 8 + j;
        float* o = &slab[(size_t)(bI * F_ + f) * L_ + lb];
        *(float4*)o       = make_float4(qs * (float)acc[0][j], qs * (float)acc[1][j],
                                        qs * (float)acc[2][j], qs * (float)acc[3][j]);
        *(float4*)(o + 4) = make_float4(qs * (float)acc[4][j], qs * (float)acc[5][j],
                                        qs * (float)acc[6][j], qs * (float)acc[7][j]);
    }
}

__global__ __launch_bounds__(256)
void adder2d_combine(const float* __restrict__ ws, float* __restrict__ out,
                     int nslab) {
    const int i = blockIdx.x * 256 + threadIdx.x;     // float4 index, SLAB/4 total
    float4 r = make_float4(0.0f, 0.0f, 0.0f, 0.0f);
    for (int s = 0; s < nslab; ++s) {
        const float4 p = ((const float4*)(ws + (size_t)s * SLAB))[i];
        r.x += p.x; r.y += p.y; r.z += p.z; r.w += p.w;
    }
    ((float4*)out)[i] = make_float4(-r.x, -r.y, -r.z, -r.w);
}

extern "C" void kernel_launch(void* const* d_in, const int* in_sizes, int n_in,
                              void* d_out, int out_size, void* d_ws, size_t ws_size,
                              hipStream_t stream) {
    const float* x = (const float*)d_in[0];   // [16,128,28,28]
    const float* W = (const float*)d_in[1];   // [128,128,3,3]
    float* out = (float*)d_out;               // [16,128,28,28]
    float* ws  = (float*)d_ws;

    int split = 0;
    if (ws_size >= (size_t)8 * SLAB * sizeof(float))      split = 8;  // 51.4 MB
    else if (ws_size >= (size_t)4 * SLAB * sizeof(float)) split = 4;  // 25.7 MB

    if (split) {
        dim3 grid(NMT, 1, split);             // 196 x split 2-wave blocks
        adder2d_main<<<grid, 128, 0, stream>>>(x, W, ws, (C_ / BC) / split, 0);
        adder2d_combine<<<SLAB / 4 / 256, 256, 0, stream>>>(ws, out, split);
    } else {
        dim3 grid(NMT, 1, 1);                 // fallback: direct, full K
        adder2d_main<<<grid, 128, 0, stream>>>(x, W, out, C_ / BC, 1);
    }
}